// Round 11
// baseline (1578.338 us; speedup 1.0000x reference)
//
#include <hip/hip_runtime.h>
#include <hip/hip_bf16.h>
#include <stdint.h>

#define H_DIM 2048
#define I_DIM 5632
#define M_DIM 8192
#define N1_DIM (2 * I_DIM)  // 11264
#define NBN1 (I_DIM / 128)  // 44 gemm1 col-blocks
#define NPART (NBN1 * 4)    // 176 partial-max slots per h row

typedef __attribute__((ext_vector_type(4))) int i32x4;

__device__ __forceinline__ void gload16(const void* g, void* l) {
  __builtin_amdgcn_global_load_lds(
      reinterpret_cast<const __attribute__((address_space(1))) uint32_t*>(
          reinterpret_cast<uintptr_t>(g)),
      reinterpret_cast<__attribute__((address_space(3))) uint32_t*>(
          reinterpret_cast<uintptr_t>(l)),
      16, 0, 0);
}

// Compiler-invisible LDS read; m0 restored inside the same asm because
// global_load_lds sets m0 to its LDS base and DS reads bounds-check vs m0.
__device__ __forceinline__ i32x4 ds_read128(uint32_t addr) {
  i32x4 d;
  asm volatile("s_mov_b32 m0, -1\n\tds_read_b128 %0, %1"
               : "=v"(d)
               : "v"(addr));
  return d;
}

// same, with compile-time byte offset immediate
#define DSR(dst, base, off)                                                    \
  asm volatile("s_mov_b32 m0, -1\n\tds_read_b128 %0, %1 offset:" off           \
               : "=v"(dst)                                                     \
               : "v"(base))

#define MEMF() asm volatile("" ::: "memory")
#define BAR()                      \
  do {                             \
    MEMF();                        \
    __builtin_amdgcn_s_barrier();  \
    MEMF();                        \
  } while (0)
#define SCHEDB() __builtin_amdgcn_sched_barrier(0)

// ---------------- per-row int8 quant of f32 matrix ----------------
__global__ __launch_bounds__(256) void quant_rows_f32(
    const float* __restrict__ in, int8_t* __restrict__ q,
    float* __restrict__ scl, int rowlen) {
  const int row = blockIdx.x;
  const int tid = threadIdx.x;
  const float* rp = in + (size_t)row * rowlen;
  float m = 0.f;
  for (int i = tid * 4; i < rowlen; i += 1024) {
    const float4 v = *reinterpret_cast<const float4*>(rp + i);
    m = fmaxf(m, fmaxf(fmaxf(fabsf(v.x), fabsf(v.y)),
                       fmaxf(fabsf(v.z), fabsf(v.w))));
  }
#pragma unroll
  for (int o = 32; o; o >>= 1) m = fmaxf(m, __shfl_xor(m, o));
  __shared__ float wm[4];
  if ((tid & 63) == 0) wm[tid >> 6] = m;
  __syncthreads();
  m = fmaxf(fmaxf(wm[0], wm[1]), fmaxf(wm[2], wm[3]));
  const float scale = fmaxf(m / 127.0f, 1e-8f);
  const float inv = 1.0f / scale;
  if (tid == 0) scl[row] = scale;
  int8_t* qp = q + (size_t)row * rowlen;
  for (int i = tid * 4; i < rowlen; i += 1024) {
    const float4 v = *reinterpret_cast<const float4*>(rp + i);
    const int a = (int)rintf(fminf(fmaxf(v.x * inv, -127.f), 127.f));
    const int b = (int)rintf(fminf(fmaxf(v.y * inv, -127.f), 127.f));
    const int c = (int)rintf(fminf(fmaxf(v.z * inv, -127.f), 127.f));
    const int d = (int)rintf(fminf(fmaxf(v.w * inv, -127.f), 127.f));
    *reinterpret_cast<int*>(qp + i) =
        (a & 255) | ((b & 255) << 8) | ((c & 255) << 16) | (d << 24);
  }
}

// -------- per-row int8 quant of bf16 h; exact f32 absmax from partials -----
__global__ __launch_bounds__(256) void quant_h_rows(
    const __hip_bfloat16* __restrict__ h, const float* __restrict__ hpart,
    int8_t* __restrict__ q, float* __restrict__ scl) {
  const int row = blockIdx.x;
  const int tid = threadIdx.x;
  float m = (tid < NPART) ? hpart[(size_t)row * NPART + tid] : 0.f;
#pragma unroll
  for (int o = 32; o; o >>= 1) m = fmaxf(m, __shfl_xor(m, o));
  __shared__ float wm[4];
  if ((tid & 63) == 0) wm[tid >> 6] = m;
  __syncthreads();
  m = fmaxf(fmaxf(wm[0], wm[1]), fmaxf(wm[2], wm[3]));
  const float scale = fmaxf(m / 127.0f, 1e-8f);
  const float inv = 1.0f / scale;
  if (tid == 0) scl[row] = scale;
  const __hip_bfloat16* rp = h + (size_t)row * I_DIM;
  int8_t* qp = q + (size_t)row * I_DIM;
  for (int i = tid * 8; i < I_DIM; i += 2048) {
    const uint4 v = *reinterpret_cast<const uint4*>(rp + i);
    const uint32_t w[4] = {v.x, v.y, v.z, v.w};
    int pk0 = 0, pk1 = 0;
#pragma unroll
    for (int j = 0; j < 8; ++j) {
      const float f =
          __uint_as_float(((w[j >> 1] >> ((j & 1) * 16)) & 0xffffu) << 16);
      const int qv = (int)rintf(fminf(fmaxf(f * inv, -127.f), 127.f));
      if (j < 4) pk0 |= (qv & 255) << ((j & 3) * 8);
      else       pk1 |= (qv & 255) << ((j & 3) * 8);
    }
    *reinterpret_cast<int2*>(qp + i) = make_int2(pk0, pk1);
  }
}

// ---- gemm2 K-loop macros (r8, unchanged) ----
#define RD_A(MH, BUF)                                                          \
  do {                                                                         \
    _Pragma("unroll") for (int m = 0; m < 4; ++m) {                            \
      a[MH][m][0] = ds_read128(aB0 + (BUF) + (MH)*16384 + m * 2048);           \
      a[MH][m][1] = ds_read128(aB1 + (BUF) + (MH)*16384 + m * 2048);           \
    }                                                                          \
  } while (0)

#define RD_B(NH, BUF)                                                          \
  do {                                                                         \
    _Pragma("unroll") for (int n = 0; n < 2; ++n) {                            \
      b[NH][n][0] = ds_read128(bB0 + (BUF) + (NH)*16384 + n * 2048);           \
      b[NH][n][1] = ds_read128(bB1 + (BUF) + (NH)*16384 + n * 2048);           \
    }                                                                          \
  } while (0)

#define MFMA_Q(MH, NH)                                                         \
  do {                                                                         \
    __builtin_amdgcn_s_setprio(1);                                             \
    _Pragma("unroll") for (int kk = 0; kk < 2; ++kk)                           \
        _Pragma("unroll") for (int m = 0; m < 4; ++m)                          \
            _Pragma("unroll") for (int n = 0; n < 2; ++n) acc[MH][m][NH][n] =  \
        __builtin_amdgcn_mfma_i32_16x16x64_i8(a[MH][m][kk], b[NH][n][kk],      \
                                              acc[MH][m][NH][n], 0, 0, 0);     \
    __builtin_amdgcn_s_setprio(0);                                             \
  } while (0)

#define KTILE_BODY(SA, SB)                                                     \
  do {                                                                         \
    const int cb = (t & 1) * 32768;                                            \
    const int nb = cb ^ 32768;                                                 \
    SCHEDB();                                                                  \
    RD_B(1, cb);                                                               \
    MEMF();                                                                    \
    if (t + 1 < KT) SA(1, t + 1);                                              \
    asm volatile("s_waitcnt lgkmcnt(4)" ::: "memory");                         \
    SCHEDB();                                                                  \
    MFMA_Q(0, 0);                                                              \
    BAR();                                                                     \
    SCHEDB();                                                                  \
    RD_A(1, cb);                                                               \
    MEMF();                                                                    \
    if (t + 1 < KT) SB(1, t + 1);                                              \
    asm volatile("s_waitcnt lgkmcnt(8)" ::: "memory");                         \
    SCHEDB();                                                                  \
    MFMA_Q(0, 1);                                                              \
    BAR();                                                                     \
    SCHEDB();                                                                  \
    if (t + 2 < KT) SA(0, t + 2);                                              \
    asm volatile("s_waitcnt lgkmcnt(0)" ::: "memory");                         \
    SCHEDB();                                                                  \
    MFMA_Q(1, 0);                                                              \
    if (t + 2 < KT) asm volatile("s_waitcnt vmcnt(6)" ::: "memory");           \
    else            asm volatile("s_waitcnt vmcnt(0)" ::: "memory");           \
    BAR();                                                                     \
    SCHEDB();                                                                  \
    if (t + 1 < KT) { RD_A(0, nb); RD_B(0, nb); }                              \
    MEMF();                                                                    \
    if (t + 2 < KT) SB(0, t + 2);                                              \
    MFMA_Q(1, 1);                                                              \
    if (t + 1 < KT) {                                                          \
      if (t + 2 < KT) asm volatile("s_waitcnt vmcnt(4)" ::: "memory");         \
      else            asm volatile("s_waitcnt vmcnt(0)" ::: "memory");         \
    }                                                                          \
    BAR();                                                                     \
  } while (0)

// ---- gemm1 BK=64 macros ----
#define RD1_A0() do { DSR(a0[0], aA, "0");    DSR(a0[1], aA, "1024");          \
                      DSR(a0[2], aA, "2048"); DSR(a0[3], aA, "3072"); } while (0)
#define RD1_A1() do { DSR(a1[0], aA, "8192"); DSR(a1[1], aA, "9216");          \
                      DSR(a1[2], aA, "10240"); DSR(a1[3], aA, "11264"); } while (0)
#define RD1_B()  do { DSR(b0[0], bA, "0");    DSR(b0[1], bA, "1024");          \
                      DSR(b1[0], bA, "8192"); DSR(b1[1], bA, "9216"); } while (0)

#define MFMA_H(MH, AV)                                                         \
  do {                                                                         \
    __builtin_amdgcn_s_setprio(1);                                             \
    _Pragma("unroll") for (int m = 0; m < 4; ++m) {                            \
      _Pragma("unroll") for (int n = 0; n < 2; ++n) {                          \
        acc[MH][m][0][n] = __builtin_amdgcn_mfma_i32_16x16x64_i8(              \
            AV[m], b0[n], acc[MH][m][0][n], 0, 0, 0);                          \
        acc[MH][m][1][n] = __builtin_amdgcn_mfma_i32_16x16x64_i8(              \
            AV[m], b1[n], acc[MH][m][1][n], 0, 0, 0);                          \
      }                                                                        \
    }                                                                          \
    __builtin_amdgcn_s_setprio(0);                                             \
  } while (0)

// =====================================================================
// GEMM1 fused: 256 rows x 128 h-cols tile, BK=64, LDS 64 KB -> 2 blocks/CU.
// Per K-tile: 12 invisible ds_reads + 32 MFMA + 4 DMAs, 2 barriers,
// counted vmcnt(4). Co-resident block hides boundary/wait stalls (m114).
// =====================================================================
__global__ __launch_bounds__(512, 4) void gemm1_silu(
    const int8_t* __restrict__ qx, const float* __restrict__ sx,
    const int8_t* __restrict__ qw, const float* __restrict__ sw,
    __hip_bfloat16* __restrict__ h, float* __restrict__ hpart) {
  __shared__ int8_t lds[65536];  // A: [0,32K) 2 bufs; B: [32K,64K) 2 bufs
  const int tid = threadIdx.x;
  const int lane = tid & 63;
  const int wid = tid >> 6;
  const int wr = wid >> 2, wc = wid & 3;
  const int c16 = lane & 15, kq = lane >> 4;

  const int nwg = gridDim.x;
  const int id = blockIdx.x;
  const int swz = (id & 7) * (nwg >> 3) + (id >> 3);
  const int bm = swz / NBN1, bn = swz % NBN1;

  // staging: 4 lanes per 64B row; 16 rows per wave
  const int srow = lane >> 2;                       // row-in-16
  const int sslot16 = ((lane & 3) ^ (srow & 3)) << 4;  // pre-swizzled slot
  const int xrow = wid * 16 + srow;                 // 0..127
  const int fx = (xrow & ~31) | ((xrow & 15) << 1) | ((xrow >> 4) & 1);

  const size_t goffA = (size_t)(bm * 256 + xrow) * H_DIM + sslot16;
  const size_t goffB = (size_t)(bn * 128 + fx) * H_DIM + sslot16;

  const uint32_t L = (uint32_t)(uintptr_t)(void*)&lds[0];
  const uint32_t aBase = L + (wr * 64 + c16) * 64 + ((kq ^ (c16 & 3)) << 4);
  const uint32_t bBase =
      L + 32768 + (wc * 32 + c16) * 64 + ((kq ^ (c16 & 3)) << 4);

#define STG1_A(t)                                                              \
  do {                                                                         \
    const int _cb = ((t) & 1) * 16384;                                         \
    gload16(qx + goffA + (size_t)(t) * 64, lds + _cb + wid * 1024);            \
    gload16(qx + goffA + (size_t)128 * H_DIM + (size_t)(t) * 64,               \
            lds + _cb + 8192 + wid * 1024);                                    \
  } while (0)

#define STG1_B(t)                                                              \
  do {                                                                         \
    const int _cb = ((t) & 1) * 16384;                                         \
    gload16(qw + goffB + (size_t)(t) * 64, lds + 32768 + _cb + wid * 1024);    \
    gload16(qw + goffB + (size_t)I_DIM * H_DIM + (size_t)(t) * 64,             \
            lds + 32768 + _cb + 8192 + wid * 1024);                            \
  } while (0)

  i32x4 acc[2][4][2][2] = {};  // [mh][m'][nh(gate/up)][n']

  const int KT = H_DIM / 64;  // 32
  // prologue: tiles 0,1 (8 DMAs); vmcnt(4) -> tile 0 landed
  STG1_A(0); STG1_B(0);
  STG1_A(1); STG1_B(1);
  asm volatile("s_waitcnt vmcnt(4)" ::: "memory");
  BAR();

#pragma unroll 1
  for (int t = 0; t < KT; ++t) {
    const int cb = (t & 1) * 16384;
    const uint32_t aA = aBase + cb;
    const uint32_t bA = bBase + cb;
    i32x4 a0[4], a1[4], b0[2], b1[2];
    RD1_A0();
    RD1_B();
    asm volatile("s_waitcnt lgkmcnt(0)" ::: "memory");
    SCHEDB();
    MFMA_H(0, a0);
    RD1_A1();
    asm volatile("s_waitcnt lgkmcnt(0)" ::: "memory");
    SCHEDB();
    BAR();  // all waves done reading buf(t&1) -> safe to overwrite
    if (t + 2 < KT) { STG1_A(t + 2); STG1_B(t + 2); }
    MEMF();
    MFMA_H(1, a1);
    if (t + 2 < KT)      asm volatile("s_waitcnt vmcnt(4)" ::: "memory");
    else if (t + 1 < KT) asm volatile("s_waitcnt vmcnt(0)" ::: "memory");
    BAR();  // tile t+1 visible to all waves
  }

  // epilogue: dequant, silu(g)*u, packed-b32 coalesced h store, partial max.
  // Lane c16 fragment n holds global h-col bn*128 + wc*32 + 2*c16 + n.
  const int row0 = bm * 256 + wr * 64 + kq * 4;
  const int colb = bn * 128 + wc * 32 + 2 * c16;
#pragma unroll
  for (int mh = 0; mh < 2; ++mh) {
#pragma unroll
    for (int m = 0; m < 4; ++m) {
#pragma unroll
      for (int r = 0; r < 4; ++r) {
        const int row = row0 + mh * 128 + m * 16 + r;
        const float sxr = sx[row];
        float hv[2];
#pragma unroll
        for (int n = 0; n < 2; ++n) {
          const int col = colb + n;
          const float g = (float)acc[mh][m][0][n][r] * (sxr * sw[col]);
          const float u = (float)acc[mh][m][1][n][r] * (sxr * sw[I_DIM + col]);
          hv[n] = g / (1.f + __expf(-g)) * u;
        }
        const uint32_t p0 = __bfloat16_as_ushort(__float2bfloat16(hv[0]));
        const uint32_t p1 = __bfloat16_as_ushort(__float2bfloat16(hv[1]));
        *reinterpret_cast<uint32_t*>(&h[(size_t)row * I_DIM + colb]) =
            p0 | (p1 << 16);
        float rmax = fmaxf(fabsf(hv[0]), fabsf(hv[1]));
#pragma unroll
        for (int o = 1; o < 16; o <<= 1)
          rmax = fmaxf(rmax, __shfl_xor(rmax, o));
        if (c16 == 0)
          hpart[(size_t)row * NPART + bn * 4 + wc] = rmax;
      }
    }
  }
}

// =====================================================================
// GEMM2: 256x256 tile, BK=128, r8 read-ahead schedule (frozen control)
// =====================================================================
__global__ __launch_bounds__(512, 2) void gemm2(
    const int8_t* __restrict__ qh, const float* __restrict__ sh,
    const int8_t* __restrict__ qw, const float* __restrict__ sw,
    float* __restrict__ out) {
  __shared__ int8_t lds[131072];
  const int tid = threadIdx.x;
  const int lane = tid & 63;
  const int wid = tid >> 6;
  const int wr = wid >> 2, wc = wid & 3;
  const int c16 = lane & 15, kq = lane >> 4, r7 = lane & 7, lr = lane >> 3;
  const int sslot = ((lane & 7) ^ lr) << 4;
  const int sl0 = (kq ^ r7) << 4;
  const int sl1 = ((4 + kq) ^ r7) << 4;

  const int nwg = gridDim.x;  // 256
  const int id = blockIdx.x;
  const int swz = (id & 7) * (nwg >> 3) + (id >> 3);
  const int NBN = H_DIM / 256;  // 8
  const int bm = swz / NBN, bn = swz % NBN;

  const size_t goffA = (size_t)(bm * 256 + wid * 8 + lr) * I_DIM + sslot;
  const size_t goffB = (size_t)(bn * 256 + wid * 8 + lr) * I_DIM + sslot;
  const int ldsAw = wid * 8 * 128;
  const int ldsBw = 65536 + wid * 8 * 128;

  const uint32_t L = (uint32_t)(uintptr_t)(void*)&lds[0];
  const uint32_t aB0 = L + (wr * 64 + c16) * 128 + sl0;
  const uint32_t aB1 = L + (wr * 64 + c16) * 128 + sl1;
  const uint32_t bB0 = L + 65536 + (wc * 32 + c16) * 128 + sl0;
  const uint32_t bB1 = L + 65536 + (wc * 32 + c16) * 128 + sl1;

  i32x4 acc[2][4][2][2] = {};
  i32x4 a[2][4][2], b[2][2][2];

#define STAGE_A2(half, t)                                                      \
  do {                                                                         \
    const int _b = ((t) & 1) * 32768;                                          \
    _Pragma("unroll") for (int ld = 0; ld < 2; ++ld)                           \
        gload16(qh + goffA + (size_t)((half)*128 + ld * 64) * I_DIM +          \
                    (size_t)(t) * 128,                                         \
                lds + _b + ldsAw + ((half)*128 + ld * 64) * 128);              \
  } while (0)

#define STAGE_B2(half, t)                                                      \
  do {                                                                         \
    const int _b = ((t) & 1) * 32768;                                          \
    _Pragma("unroll") for (int ld = 0; ld < 2; ++ld)                           \
        gload16(qw + goffB + (size_t)((half)*128 + ld * 64) * I_DIM +          \
                    (size_t)(t) * 128,                                         \
                lds + _b + ldsBw + ((half)*128 + ld * 64) * 128);              \
  } while (0)

  const int KT = I_DIM / 128;  // 44
  STAGE_A2(0, 0); STAGE_B2(0, 0); STAGE_A2(1, 0); STAGE_B2(1, 0);
  STAGE_A2(0, 1); STAGE_B2(0, 1);
  asm volatile("s_waitcnt vmcnt(4)" ::: "memory");
  BAR();
  RD_A(0, 0); RD_B(0, 0);
  MEMF();

#pragma unroll 1
  for (int t = 0; t < KT; ++t) {
    KTILE_BODY(STAGE_A2, STAGE_B2);
  }

  const int row0 = bm * 256 + wr * 64 + kq * 4;
  const int col0 = bn * 256 + wc * 32 + c16;
#pragma unroll
  for (int mh = 0; mh < 2; ++mh) {
#pragma unroll
    for (int m = 0; m < 4; ++m) {
#pragma unroll
      for (int r = 0; r < 4; ++r) {
        const int row = row0 + mh * 128 + m * 16 + r;
        const float shr = sh[row];
#pragma unroll
        for (int nh = 0; nh < 2; ++nh) {
#pragma unroll
          for (int n = 0; n < 2; ++n) {
            const int col = col0 + nh * 128 + n * 16;
            out[(size_t)row * H_DIM + col] =
                (float)acc[mh][m][nh][n][r] * (shr * sw[col]);
          }
        }
      }
    }
  }
}

extern "C" void kernel_launch(void* const* d_in, const int* in_sizes, int n_in,
                              void* d_out, int out_size, void* d_ws, size_t ws_size,
                              hipStream_t stream) {
  (void)in_sizes; (void)n_in; (void)out_size; (void)ws_size;
  const float* x  = (const float*)d_in[0];
  const float* w1 = (const float*)d_in[1];
  const float* w2 = (const float*)d_in[2];
  float* out = (float*)d_out;

  size_t off = 0;
  auto alloc = [&](size_t n) {
    void* p = (char*)d_ws + off;
    off += (n + 255) & ~(size_t)255;
    return p;
  };
  int8_t* qx  = (int8_t*)alloc((size_t)M_DIM * H_DIM);
  int8_t* qw1 = (int8_t*)alloc((size_t)N1_DIM * H_DIM);
  int8_t* qw2 = (int8_t*)alloc((size_t)H_DIM * I_DIM);
  int8_t* qh  = (int8_t*)alloc((size_t)M_DIM * I_DIM);
  __hip_bfloat16* hb = (__hip_bfloat16*)alloc((size_t)M_DIM * I_DIM * 2);
  float* sx    = (float*)alloc((size_t)M_DIM * 4);
  float* sw1   = (float*)alloc((size_t)N1_DIM * 4);
  float* sw2   = (float*)alloc((size_t)H_DIM * 4);
  float* shs   = (float*)alloc((size_t)M_DIM * 4);
  float* hpart = (float*)alloc((size_t)M_DIM * NPART * 4);  // 5.8 MiB

  quant_rows_f32<<<M_DIM, 256, 0, stream>>>(x, qx, sx, H_DIM);
  quant_rows_f32<<<N1_DIM, 256, 0, stream>>>(w1, qw1, sw1, H_DIM);
  quant_rows_f32<<<H_DIM, 256, 0, stream>>>(w2, qw2, sw2, I_DIM);
  gemm1_silu<<<(M_DIM / 256) * NBN1, 512, 0, stream>>>(
      qx, sx, qw1, sw1, hb, hpart);
  quant_h_rows<<<M_DIM, 256, 0, stream>>>(hb, hpart, qh, shs);
  gemm2<<<(M_DIM / 256) * (H_DIM / 256), 512, 0, stream>>>(
      qh, shs, qw2, sw2, out);
}

// Round 12
// 397.976 us; speedup vs baseline: 3.9659x; 3.9659x over previous
//
#include <hip/hip_runtime.h>
#include <hip/hip_bf16.h>
#include <stdint.h>

#define H_DIM 2048
#define I_DIM 5632
#define M_DIM 8192
#define N1_DIM (2 * I_DIM)  // 11264
#define NBN1 (I_DIM / 128)  // 44 gemm1 col-blocks
#define NPART (NBN1 * 4)    // 176 partial-max slots per h row

typedef __attribute__((ext_vector_type(4))) int i32x4;

__device__ __forceinline__ void gload16(const void* g, void* l) {
  __builtin_amdgcn_global_load_lds(
      reinterpret_cast<const __attribute__((address_space(1))) uint32_t*>(
          reinterpret_cast<uintptr_t>(g)),
      reinterpret_cast<__attribute__((address_space(3))) uint32_t*>(
          reinterpret_cast<uintptr_t>(l)),
      16, 0, 0);
}

// Compiler-invisible LDS read; m0 restored inside the same asm because
// global_load_lds sets m0 to its LDS base and DS reads bounds-check vs m0.
__device__ __forceinline__ i32x4 ds_read128(uint32_t addr) {
  i32x4 d;
  asm volatile("s_mov_b32 m0, -1\n\tds_read_b128 %0, %1"
               : "=v"(d)
               : "v"(addr));
  return d;
}

#define MEMF() asm volatile("" ::: "memory")
#define BAR()                      \
  do {                             \
    MEMF();                        \
    __builtin_amdgcn_s_barrier();  \
    MEMF();                        \
  } while (0)
#define SCHEDB() __builtin_amdgcn_sched_barrier(0)

// ---------------- per-row int8 quant of f32 matrix ----------------
__global__ __launch_bounds__(256) void quant_rows_f32(
    const float* __restrict__ in, int8_t* __restrict__ q,
    float* __restrict__ scl, int rowlen) {
  const int row = blockIdx.x;
  const int tid = threadIdx.x;
  const float* rp = in + (size_t)row * rowlen;
  float m = 0.f;
  for (int i = tid * 4; i < rowlen; i += 1024) {
    const float4 v = *reinterpret_cast<const float4*>(rp + i);
    m = fmaxf(m, fmaxf(fmaxf(fabsf(v.x), fabsf(v.y)),
                       fmaxf(fabsf(v.z), fabsf(v.w))));
  }
#pragma unroll
  for (int o = 32; o; o >>= 1) m = fmaxf(m, __shfl_xor(m, o));
  __shared__ float wm[4];
  if ((tid & 63) == 0) wm[tid >> 6] = m;
  __syncthreads();
  m = fmaxf(fmaxf(wm[0], wm[1]), fmaxf(wm[2], wm[3]));
  const float scale = fmaxf(m / 127.0f, 1e-8f);
  const float inv = 1.0f / scale;
  if (tid == 0) scl[row] = scale;
  int8_t* qp = q + (size_t)row * rowlen;
  for (int i = tid * 4; i < rowlen; i += 1024) {
    const float4 v = *reinterpret_cast<const float4*>(rp + i);
    const int a = (int)rintf(fminf(fmaxf(v.x * inv, -127.f), 127.f));
    const int b = (int)rintf(fminf(fmaxf(v.y * inv, -127.f), 127.f));
    const int c = (int)rintf(fminf(fmaxf(v.z * inv, -127.f), 127.f));
    const int d = (int)rintf(fminf(fmaxf(v.w * inv, -127.f), 127.f));
    *reinterpret_cast<int*>(qp + i) =
        (a & 255) | ((b & 255) << 8) | ((c & 255) << 16) | (d << 24);
  }
}

// -------- per-row int8 quant of bf16 h; exact f32 absmax from partials -----
__global__ __launch_bounds__(256) void quant_h_rows(
    const __hip_bfloat16* __restrict__ h, const float* __restrict__ hpart,
    int8_t* __restrict__ q, float* __restrict__ scl) {
  const int row = blockIdx.x;
  const int tid = threadIdx.x;
  float m = (tid < NPART) ? hpart[(size_t)row * NPART + tid] : 0.f;
#pragma unroll
  for (int o = 32; o; o >>= 1) m = fmaxf(m, __shfl_xor(m, o));
  __shared__ float wm[4];
  if ((tid & 63) == 0) wm[tid >> 6] = m;
  __syncthreads();
  m = fmaxf(fmaxf(wm[0], wm[1]), fmaxf(wm[2], wm[3]));
  const float scale = fmaxf(m / 127.0f, 1e-8f);
  const float inv = 1.0f / scale;
  if (tid == 0) scl[row] = scale;
  const __hip_bfloat16* rp = h + (size_t)row * I_DIM;
  int8_t* qp = q + (size_t)row * I_DIM;
  for (int i = tid * 8; i < I_DIM; i += 2048) {
    const uint4 v = *reinterpret_cast<const uint4*>(rp + i);
    const uint32_t w[4] = {v.x, v.y, v.z, v.w};
    int pk0 = 0, pk1 = 0;
#pragma unroll
    for (int j = 0; j < 8; ++j) {
      const float f =
          __uint_as_float(((w[j >> 1] >> ((j & 1) * 16)) & 0xffffu) << 16);
      const int qv = (int)rintf(fminf(fmaxf(f * inv, -127.f), 127.f));
      if (j < 4) pk0 |= (qv & 255) << ((j & 3) * 8);
      else       pk1 |= (qv & 255) << ((j & 3) * 8);
    }
    *reinterpret_cast<int2*>(qp + i) = make_int2(pk0, pk1);
  }
}

// ---- shared K-loop macros (read-ahead 4-quad schedule) ----
#define RD_A(MH, BUF)                                                          \
  do {                                                                         \
    _Pragma("unroll") for (int m = 0; m < 4; ++m) {                            \
      a[MH][m][0] = ds_read128(aB0 + (BUF) + (MH)*16384 + m * 2048);           \
      a[MH][m][1] = ds_read128(aB1 + (BUF) + (MH)*16384 + m * 2048);           \
    }                                                                          \
  } while (0)

#define RD_B(NH, BUF)                                                          \
  do {                                                                         \
    _Pragma("unroll") for (int n = 0; n < 2; ++n) {                            \
      b[NH][n][0] = ds_read128(bB0 + (BUF) + (NH)*16384 + n * 2048);           \
      b[NH][n][1] = ds_read128(bB1 + (BUF) + (NH)*16384 + n * 2048);           \
    }                                                                          \
  } while (0)

#define MFMA_Q(MH, NH)                                                         \
  do {                                                                         \
    __builtin_amdgcn_s_setprio(1);                                             \
    _Pragma("unroll") for (int kk = 0; kk < 2; ++kk)                           \
        _Pragma("unroll") for (int m = 0; m < 4; ++m)                          \
            _Pragma("unroll") for (int n = 0; n < 2; ++n) acc[MH][m][NH][n] =  \
        __builtin_amdgcn_mfma_i32_16x16x64_i8(a[MH][m][kk], b[NH][n][kk],      \
                                              acc[MH][m][NH][n], 0, 0, 0);     \
    __builtin_amdgcn_s_setprio(0);                                             \
  } while (0)

// one K-tile, read-ahead schedule. SA/SB are the stage macros.
#define KTILE_BODY(SA, SB)                                                     \
  do {                                                                         \
    const int cb = (t & 1) * 32768;                                            \
    const int nb = cb ^ 32768;                                                 \
    /* Q00 */                                                                  \
    SCHEDB();                                                                  \
    RD_B(1, cb);                                                               \
    MEMF();                                                                    \
    if (t + 1 < KT) SA(1, t + 1);                                              \
    asm volatile("s_waitcnt lgkmcnt(4)" ::: "memory");                         \
    SCHEDB();                                                                  \
    MFMA_Q(0, 0);                                                              \
    BAR();                                                                     \
    /* Q01 */                                                                  \
    SCHEDB();                                                                  \
    RD_A(1, cb);                                                               \
    MEMF();                                                                    \
    if (t + 1 < KT) SB(1, t + 1);                                              \
    asm volatile("s_waitcnt lgkmcnt(8)" ::: "memory");                         \
    SCHEDB();                                                                  \
    MFMA_Q(0, 1);                                                              \
    BAR();                                                                     \
    /* Q10 */                                                                  \
    SCHEDB();                                                                  \
    if (t + 2 < KT) SA(0, t + 2);                                              \
    asm volatile("s_waitcnt lgkmcnt(0)" ::: "memory");                         \
    SCHEDB();                                                                  \
    MFMA_Q(1, 0);                                                              \
    if (t + 2 < KT) asm volatile("s_waitcnt vmcnt(6)" ::: "memory");           \
    else            asm volatile("s_waitcnt vmcnt(0)" ::: "memory");           \
    BAR();                                                                     \
    /* Q11 */                                                                  \
    SCHEDB();                                                                  \
    if (t + 1 < KT) { RD_A(0, nb); RD_B(0, nb); }                              \
    MEMF();                                                                    \
    if (t + 2 < KT) SB(0, t + 2);                                              \
    MFMA_Q(1, 1);                                                              \
    if (t + 1 < KT) {                                                          \
      if (t + 2 < KT) asm volatile("s_waitcnt vmcnt(4)" ::: "memory");         \
      else            asm volatile("s_waitcnt vmcnt(0)" ::: "memory");         \
    }                                                                          \
    BAR();                                                                     \
  } while (0)

// =====================================================================
// GEMM1 fused: 256x256 tile, BK=128, 8 waves, read-ahead 4-quad schedule
// (r8 loop, unchanged). NEW: XCD-rectangular tile mapping — each XCD owns
// a 16bm x 11bn rectangle (176 = 16*11 exact), traversed bn-fastest, so
// the 11 B-panels are L2-reused 16x and concurrent blocks share live
// K-slices. Replaces the bm-row mapping whose B-panels streamed from L3.
// =====================================================================
__global__ __launch_bounds__(512, 2) void gemm1_silu(
    const int8_t* __restrict__ qx, const float* __restrict__ sx,
    const int8_t* __restrict__ qw, const float* __restrict__ sw,
    __hip_bfloat16* __restrict__ h, float* __restrict__ hpart) {
  __shared__ int8_t lds[131072];  // A: [0,64K) 2 bufs; B: [64K,128K) 2 bufs
  const int tid = threadIdx.x;
  const int lane = tid & 63;
  const int wid = tid >> 6;
  const int wr = wid >> 2, wc = wid & 3;
  const int c16 = lane & 15, kq = lane >> 4, r7 = lane & 7, lr = lane >> 3;
  const int sslot = ((lane & 7) ^ lr) << 4;
  const int sl0 = (kq ^ r7) << 4;
  const int sl1 = ((4 + kq) ^ r7) << 4;

  // XCD-rectangular mapping (dispatch round-robins blockIdx over 8 XCDs)
  const int id = blockIdx.x;
  const int x = id & 7;    // XCD
  const int j = id >> 3;   // 0..175 within XCD
  const int bm = ((x & 1) << 4) + j / 11;       // 16-row band per XCD parity
  const int bn = (x >> 1) * 11 + j % 11;        // 11-col band per XCD pair

  // interleave permutation for B rows: LDS row x holds global B-row f(x)
  const int xrow = wid * 8 + lr;
  const int fx = (xrow & ~31) | ((xrow & 15) << 1) | ((xrow >> 4) & 1);

  const size_t goffA = (size_t)(bm * 256 + xrow) * H_DIM + sslot;
  const size_t goffG = (size_t)(bn * 128 + fx) * H_DIM + sslot;
  const size_t goffU = goffG + (size_t)I_DIM * H_DIM;
  const int ldsAw = wid * 8 * 128;
  const int ldsBw = 65536 + wid * 8 * 128;

  const uint32_t L = (uint32_t)(uintptr_t)(void*)&lds[0];
  const uint32_t aB0 = L + (wr * 64 + c16) * 128 + sl0;
  const uint32_t aB1 = L + (wr * 64 + c16) * 128 + sl1;
  const uint32_t bB0 = L + 65536 + (wc * 32 + c16) * 128 + sl0;
  const uint32_t bB1 = L + 65536 + (wc * 32 + c16) * 128 + sl1;

  i32x4 acc[2][4][2][2] = {};  // [mh][m'][nh(gate/up)][n']
  i32x4 a[2][4][2], b[2][2][2];

#define STAGE_A1(half, t)                                                      \
  do {                                                                         \
    const int _b = ((t) & 1) * 32768;                                          \
    _Pragma("unroll") for (int ld = 0; ld < 2; ++ld)                           \
        gload16(qx + goffA + (size_t)((half)*128 + ld * 64) * H_DIM +          \
                    (size_t)(t) * 128,                                         \
                lds + _b + ldsAw + ((half)*128 + ld * 64) * 128);              \
  } while (0)

#define STAGE_B1(half, t)                                                      \
  do {                                                                         \
    const int _b = ((t) & 1) * 32768;                                          \
    const int8_t* _s = (half) ? (qw + goffU) : (qw + goffG);                   \
    _Pragma("unroll") for (int ld = 0; ld < 2; ++ld)                           \
        gload16(_s + (size_t)(ld * 64) * H_DIM + (size_t)(t) * 128,            \
                lds + _b + ldsBw + ((half)*128 + ld * 64) * 128);              \
  } while (0)

  const int KT = H_DIM / 128;  // 16
  // prologue: 6 stages; vmcnt(4) -> A0B0(0),A1B1(0) landed; read tile-0 frags
  STAGE_A1(0, 0); STAGE_B1(0, 0); STAGE_A1(1, 0); STAGE_B1(1, 0);
  STAGE_A1(0, 1); STAGE_B1(0, 1);
  asm volatile("s_waitcnt vmcnt(4)" ::: "memory");
  BAR();
  RD_A(0, 0); RD_B(0, 0);
  MEMF();

#pragma unroll 1
  for (int t = 0; t < KT; ++t) {
    KTILE_BODY(STAGE_A1, STAGE_B1);
  }

  // epilogue: dequant, silu(g)*u, packed-b32 coalesced h store, partial max.
  const int row0 = bm * 256 + wr * 64 + kq * 4;
  const int colb = bn * 128 + wc * 32 + 2 * c16;
#pragma unroll
  for (int mh = 0; mh < 2; ++mh) {
#pragma unroll
    for (int m = 0; m < 4; ++m) {
#pragma unroll
      for (int r = 0; r < 4; ++r) {
        const int row = row0 + mh * 128 + m * 16 + r;
        const float sxr = sx[row];
        float hv[2];
#pragma unroll
        for (int n = 0; n < 2; ++n) {
          const int col = colb + n;
          const float g = (float)acc[mh][m][0][n][r] * (sxr * sw[col]);
          const float u = (float)acc[mh][m][1][n][r] * (sxr * sw[I_DIM + col]);
          hv[n] = g / (1.f + __expf(-g)) * u;
        }
        const uint32_t p0 = __bfloat16_as_ushort(__float2bfloat16(hv[0]));
        const uint32_t p1 = __bfloat16_as_ushort(__float2bfloat16(hv[1]));
        *reinterpret_cast<uint32_t*>(&h[(size_t)row * I_DIM + colb]) =
            p0 | (p1 << 16);
        float rmax = fmaxf(fabsf(hv[0]), fabsf(hv[1]));
#pragma unroll
        for (int o = 1; o < 16; o <<= 1)
          rmax = fmaxf(rmax, __shfl_xor(rmax, o));
        if (c16 == 0)
          hpart[(size_t)row * NPART + bn * 4 + wc] = rmax;
      }
    }
  }
}

// =====================================================================
// GEMM2: 256x256 tile, BK=128, r8 read-ahead schedule (frozen control)
// =====================================================================
__global__ __launch_bounds__(512, 2) void gemm2(
    const int8_t* __restrict__ qh, const float* __restrict__ sh,
    const int8_t* __restrict__ qw, const float* __restrict__ sw,
    float* __restrict__ out) {
  __shared__ int8_t lds[131072];
  const int tid = threadIdx.x;
  const int lane = tid & 63;
  const int wid = tid >> 6;
  const int wr = wid >> 2, wc = wid & 3;
  const int c16 = lane & 15, kq = lane >> 4, r7 = lane & 7, lr = lane >> 3;
  const int sslot = ((lane & 7) ^ lr) << 4;
  const int sl0 = (kq ^ r7) << 4;
  const int sl1 = ((4 + kq) ^ r7) << 4;

  const int nwg = gridDim.x;  // 256
  const int id = blockIdx.x;
  const int swz = (id & 7) * (nwg >> 3) + (id >> 3);
  const int NBN = H_DIM / 256;  // 8
  const int bm = swz / NBN, bn = swz % NBN;

  const size_t goffA = (size_t)(bm * 256 + wid * 8 + lr) * I_DIM + sslot;
  const size_t goffB = (size_t)(bn * 256 + wid * 8 + lr) * I_DIM + sslot;
  const int ldsAw = wid * 8 * 128;
  const int ldsBw = 65536 + wid * 8 * 128;

  const uint32_t L = (uint32_t)(uintptr_t)(void*)&lds[0];
  const uint32_t aB0 = L + (wr * 64 + c16) * 128 + sl0;
  const uint32_t aB1 = L + (wr * 64 + c16) * 128 + sl1;
  const uint32_t bB0 = L + 65536 + (wc * 32 + c16) * 128 + sl0;
  const uint32_t bB1 = L + 65536 + (wc * 32 + c16) * 128 + sl1;

  i32x4 acc[2][4][2][2] = {};
  i32x4 a[2][4][2], b[2][2][2];

#define STAGE_A2(half, t)                                                      \
  do {                                                                         \
    const int _b = ((t) & 1) * 32768;                                          \
    _Pragma("unroll") for (int ld = 0; ld < 2; ++ld)                           \
        gload16(qh + goffA + (size_t)((half)*128 + ld * 64) * I_DIM +          \
                    (size_t)(t) * 128,                                         \
                lds + _b + ldsAw + ((half)*128 + ld * 64) * 128);              \
  } while (0)

#define STAGE_B2(half, t)                                                      \
  do {                                                                         \
    const int _b = ((t) & 1) * 32768;                                          \
    _Pragma("unroll") for (int ld = 0; ld < 2; ++ld)                           \
        gload16(qw + goffB + (size_t)((half)*128 + ld * 64) * I_DIM +          \
                    (size_t)(t) * 128,                                         \
                lds + _b + ldsBw + ((half)*128 + ld * 64) * 128);              \
  } while (0)

  const int KT = I_DIM / 128;  // 44
  STAGE_A2(0, 0); STAGE_B2(0, 0); STAGE_A2(1, 0); STAGE_B2(1, 0);
  STAGE_A2(0, 1); STAGE_B2(0, 1);
  asm volatile("s_waitcnt vmcnt(4)" ::: "memory");
  BAR();
  RD_A(0, 0); RD_B(0, 0);
  MEMF();

#pragma unroll 1
  for (int t = 0; t < KT; ++t) {
    KTILE_BODY(STAGE_A2, STAGE_B2);
  }

  const int row0 = bm * 256 + wr * 64 + kq * 4;
  const int col0 = bn * 256 + wc * 32 + c16;
#pragma unroll
  for (int mh = 0; mh < 2; ++mh) {
#pragma unroll
    for (int m = 0; m < 4; ++m) {
#pragma unroll
      for (int r = 0; r < 4; ++r) {
        const int row = row0 + mh * 128 + m * 16 + r;
        const float shr = sh[row];
#pragma unroll
        for (int nh = 0; nh < 2; ++nh) {
#pragma unroll
          for (int n = 0; n < 2; ++n) {
            const int col = col0 + nh * 128 + n * 16;
            out[(size_t)row * H_DIM + col] =
                (float)acc[mh][m][nh][n][r] * (shr * sw[col]);
          }
        }
      }
    }
  }
}

extern "C" void kernel_launch(void* const* d_in, const int* in_sizes, int n_in,
                              void* d_out, int out_size, void* d_ws, size_t ws_size,
                              hipStream_t stream) {
  (void)in_sizes; (void)n_in; (void)out_size; (void)ws_size;
  const float* x  = (const float*)d_in[0];
  const float* w1 = (const float*)d_in[1];
  const float* w2 = (const float*)d_in[2];
  float* out = (float*)d_out;

  size_t off = 0;
  auto alloc = [&](size_t n) {
    void* p = (char*)d_ws + off;
    off += (n + 255) & ~(size_t)255;
    return p;
  };
  int8_t* qx  = (int8_t*)alloc((size_t)M_DIM * H_DIM);
  int8_t* qw1 = (int8_t*)alloc((size_t)N1_DIM * H_DIM);
  int8_t* qw2 = (int8_t*)alloc((size_t)H_DIM * I_DIM);
  int8_t* qh  = (int8_t*)alloc((size_t)M_DIM * I_DIM);
  __hip_bfloat16* hb = (__hip_bfloat16*)alloc((size_t)M_DIM * I_DIM * 2);
  float* sx    = (float*)alloc((size_t)M_DIM * 4);
  float* sw1   = (float*)alloc((size_t)N1_DIM * 4);
  float* sw2   = (float*)alloc((size_t)H_DIM * 4);
  float* shs   = (float*)alloc((size_t)M_DIM * 4);
  float* hpart = (float*)alloc((size_t)M_DIM * NPART * 4);  // 5.8 MiB

  quant_rows_f32<<<M_DIM, 256, 0, stream>>>(x, qx, sx, H_DIM);
  quant_rows_f32<<<N1_DIM, 256, 0, stream>>>(w1, qw1, sw1, H_DIM);
  quant_rows_f32<<<H_DIM, 256, 0, stream>>>(w2, qw2, sw2, I_DIM);
  gemm1_silu<<<(M_DIM / 256) * NBN1, 512, 0, stream>>>(
      qx, sx, qw1, sw1, hb, hpart);
  quant_h_rows<<<M_DIM, 256, 0, stream>>>(hb, hpart, qh, shs);
  gemm2<<<(M_DIM / 256) * (H_DIM / 256), 512, 0, stream>>>(
      qh, shs, qw2, sw2, out);
}